// Round 1
// baseline (160.643 us; speedup 1.0000x reference)
//
#include <hip/hip_runtime.h>

#define D 300
#define NF4 75            // 300 floats = 75 float4 per row
#define K 10
#define WAVES_PER_BLOCK 4

// ---------------- Kernel A: cosine + per-block top-10 candidates ----------------
__global__ __launch_bounds__(256) void cos_topk_partial(
    const float* __restrict__ emb, const float* __restrict__ wvec,
    float* __restrict__ cand_v, int* __restrict__ cand_i,
    int V, int totalWaves)
{
    const int lane = threadIdx.x & 63;
    const int wid  = threadIdx.x >> 6;
    const int gw   = blockIdx.x * WAVES_PER_BLOCK + wid;

    // Preload w (wave-uniform across rows): lane reads float4 'lane', lanes<11 read 'lane+64'
    const float4* w4 = (const float4*)wvec;
    float4 wa = w4[lane];
    float4 wb = make_float4(0.f, 0.f, 0.f, 0.f);
    if (lane < NF4 - 64) wb = w4[64 + lane];

    // q norm (wave reduce once)
    float qsq = wa.x*wa.x + wa.y*wa.y + wa.z*wa.z + wa.w*wa.w
              + wb.x*wb.x + wb.y*wb.y + wb.z*wb.z + wb.w*wb.w;
    #pragma unroll
    for (int m = 32; m >= 1; m >>= 1) qsq += __shfl_xor(qsq, m, 64);
    const float qn = sqrtf(qsq);

    // per-wave top-10 (wave-uniform values -> uniform control flow)
    float tv[K]; int ti[K];
    #pragma unroll
    for (int j = 0; j < K; ++j) { tv[j] = -1e30f; ti[j] = 0; }

    for (int r = gw; r < V; r += totalWaves) {
        const float4* rp = (const float4*)(emb + (size_t)r * D);
        float4 a = rp[lane];
        float4 b = make_float4(0.f, 0.f, 0.f, 0.f);
        if (lane < NF4 - 64) b = rp[64 + lane];

        float dot = a.x*wa.x + a.y*wa.y + a.z*wa.z + a.w*wa.w
                  + b.x*wb.x + b.y*wb.y + b.z*wb.z + b.w*wb.w;
        float sq  = a.x*a.x + a.y*a.y + a.z*a.z + a.w*a.w
                  + b.x*b.x + b.y*b.y + b.z*b.z + b.w*b.w;
        #pragma unroll
        for (int m = 32; m >= 1; m >>= 1) {
            dot += __shfl_xor(dot, m, 64);
            sq  += __shfl_xor(sq,  m, 64);
        }
        float c = dot / (sqrtf(sq + 1e-9f) * qn);

        if (c > tv[K-1]) {                 // wave-uniform branch
            tv[K-1] = c; ti[K-1] = r;
            #pragma unroll
            for (int j = K-1; j > 0; --j) {
                if (tv[j] > tv[j-1]) {
                    float t = tv[j]; tv[j] = tv[j-1]; tv[j-1] = t;
                    int   u = ti[j]; ti[j] = ti[j-1]; ti[j-1] = u;
                }
            }
        }
    }

    // merge the block's 4 waves in LDS -> block top-10
    __shared__ float sv[WAVES_PER_BLOCK * K];
    __shared__ int   si[WAVES_PER_BLOCK * K];
    if (lane == 0) {
        #pragma unroll
        for (int j = 0; j < K; ++j) { sv[wid*K + j] = tv[j]; si[wid*K + j] = ti[j]; }
    }
    __syncthreads();
    if (threadIdx.x == 0) {
        float bv[K]; int bi[K];
        #pragma unroll
        for (int j = 0; j < K; ++j) { bv[j] = -1e30f; bi[j] = 0; }
        for (int t = 0; t < WAVES_PER_BLOCK * K; ++t) {
            float c = sv[t]; int r = si[t];
            if (c > bv[K-1]) {
                bv[K-1] = c; bi[K-1] = r;
                #pragma unroll
                for (int j = K-1; j > 0; --j) {
                    if (bv[j] > bv[j-1]) {
                        float t2 = bv[j]; bv[j] = bv[j-1]; bv[j-1] = t2;
                        int   u2 = bi[j]; bi[j] = bi[j-1]; bi[j-1] = u2;
                    }
                }
            }
        }
        #pragma unroll
        for (int j = 0; j < K; ++j) {
            cand_v[blockIdx.x*K + j] = bv[j];
            cand_i[blockIdx.x*K + j] = bi[j];
        }
    }
}

// ---------------- Kernel B: reduce candidates to global top-10 ----------------
__global__ __launch_bounds__(1024) void topk_final(
    float* __restrict__ cand_v, const int* __restrict__ cand_i,
    int nc, float* __restrict__ out)
{
    __shared__ float rv[16];
    __shared__ int   rp[16];
    const int tid  = threadIdx.x;
    const int lane = tid & 63;
    const int wid  = tid >> 6;

    for (int p = 0; p < K; ++p) {
        float bestv = -1e30f; int bestpos = 0x7fffffff;
        for (int t = tid; t < nc; t += 1024) {
            float v = cand_v[t];
            if (v > bestv || (v == bestv && t < bestpos)) { bestv = v; bestpos = t; }
        }
        #pragma unroll
        for (int m = 32; m >= 1; m >>= 1) {
            float ov = __shfl_xor(bestv, m, 64);
            int   op = __shfl_xor(bestpos, m, 64);
            if (ov > bestv || (ov == bestv && op < bestpos)) { bestv = ov; bestpos = op; }
        }
        if (lane == 0) { rv[wid] = bestv; rp[wid] = bestpos; }
        __syncthreads();
        if (tid == 0) {
            float bv = rv[0]; int bp = rp[0];
            for (int i = 1; i < 16; ++i)
                if (rv[i] > bv || (rv[i] == bv && rp[i] < bp)) { bv = rv[i]; bp = rp[i]; }
            out[p]     = bv;                       // value
            out[K + p] = (float)cand_i[bp];        // index (numeric, exact < 2^24)
            cand_v[bp] = -1e31f;                   // exclude for next pass
        }
        __syncthreads();
    }
}

extern "C" void kernel_launch(void* const* d_in, const int* in_sizes, int n_in,
                              void* d_out, int out_size, void* d_ws, size_t ws_size,
                              hipStream_t stream) {
    const float* emb  = (const float*)d_in[0];
    const float* wvec = (const float*)d_in[1];
    const int V = in_sizes[0] / D;

    int nblocks = 1024;
    size_t need = (size_t)nblocks * K * 8;  // vals + idx
    if (need > ws_size) {
        nblocks = (int)(ws_size / (K * 8));
        if (nblocks < 1) nblocks = 1;
    }

    float* cand_v = (float*)d_ws;
    int*   cand_i = (int*)((float*)d_ws + (size_t)nblocks * K);

    cos_topk_partial<<<nblocks, 256, 0, stream>>>(emb, wvec, cand_v, cand_i,
                                                  V, nblocks * WAVES_PER_BLOCK);
    topk_final<<<1, 1024, 0, stream>>>(cand_v, cand_i, nblocks * K, (float*)d_out);
}

// Round 2
// 133.288 us; speedup vs baseline: 1.2052x; 1.2052x over previous
//
#include <hip/hip_runtime.h>

#define D    300
#define NF4  75            // 300 floats = 75 float4 per row
#define K    10
#define WPB  4             // waves per block
#define GPB  16            // 16-lane row-groups per block (4 per wave)
#define NBLOCKS 2048
#define CPT  20            // candidates per thread in final kernel (NBLOCKS*K/1024)

__device__ __forceinline__ float d4(float4 a, float4 b) {
    return a.x*b.x + a.y*b.y + a.z*b.z + a.w*b.w;
}

// ---------------- Kernel A: cosine + per-block top-10 candidates ----------------
// 16 lanes per row, 4 rows per wave per iteration.
__global__ __launch_bounds__(256) void cos_topk_partial(
    const float* __restrict__ emb, const float* __restrict__ wvec,
    float* __restrict__ cand_v, int* __restrict__ cand_i,
    int V, int totalGroups)
{
    const int tid  = threadIdx.x;
    const int lane = tid & 63;
    const int wid  = tid >> 6;
    const int l16  = lane & 15;      // position within row-group
    const int rg   = lane >> 4;      // row-group 0..3 within wave

    // Preload w: lane needs w4[l16 + 16j], j=0..3, plus masked j=4
    const float4* w4p = (const float4*)wvec;
    float4 w0 = w4p[l16];
    float4 w1 = w4p[l16 + 16];
    float4 w2 = w4p[l16 + 32];
    float4 w3 = w4p[l16 + 48];
    float4 w4t = make_float4(0.f, 0.f, 0.f, 0.f);
    if (l16 < NF4 - 64) w4t = w4p[l16 + 64];

    // q norm: 16-lane group reduce
    float qsq = d4(w0,w0) + d4(w1,w1) + d4(w2,w2) + d4(w3,w3) + d4(w4t,w4t);
    #pragma unroll
    for (int m = 8; m >= 1; m >>= 1) qsq += __shfl_xor(qsq, m, 64);
    const float qn = sqrtf(qsq);

    // per-group top-10 (group-uniform values -> uniform control flow in group)
    float tv[K]; int ti[K];
    #pragma unroll
    for (int j = 0; j < K; ++j) { tv[j] = -1e30f; ti[j] = 0; }

    const int g0 = (blockIdx.x * WPB + wid) * 4 + rg;
    for (int r = g0; r < V; r += totalGroups) {
        const float4* rp = (const float4*)(emb + (size_t)r * D);
        float4 a0 = rp[l16];
        float4 a1 = rp[l16 + 16];
        float4 a2 = rp[l16 + 32];
        float4 a3 = rp[l16 + 48];
        float4 a4 = make_float4(0.f, 0.f, 0.f, 0.f);
        if (l16 < NF4 - 64) a4 = rp[l16 + 64];

        // two accumulator pairs to shorten FMA dep chains
        float da = d4(a0, w0) + d4(a1, w1);
        float db = d4(a2, w2) + d4(a3, w3) + d4(a4, w4t);
        float sa = d4(a0, a0) + d4(a1, a1);
        float sb = d4(a2, a2) + d4(a3, a3) + d4(a4, a4);
        float dot = da + db;
        float sq  = sa + sb;

        #pragma unroll
        for (int m = 8; m >= 1; m >>= 1) {
            dot += __shfl_xor(dot, m, 64);
            sq  += __shfl_xor(sq,  m, 64);
        }
        float c = dot / (sqrtf(sq + 1e-9f) * qn);

        if (c > tv[K-1]) {             // group-uniform branch
            tv[K-1] = c; ti[K-1] = r;
            #pragma unroll
            for (int j = K-1; j > 0; --j) {
                if (tv[j] > tv[j-1]) {
                    float t = tv[j]; tv[j] = tv[j-1]; tv[j-1] = t;
                    int   u = ti[j]; ti[j] = ti[j-1]; ti[j-1] = u;
                }
            }
        }
    }

    // merge the block's 16 groups in LDS -> block top-10
    __shared__ float sv[GPB * K];
    __shared__ int   si[GPB * K];
    if (l16 == 0) {
        const int gidx = wid * 4 + rg;
        #pragma unroll
        for (int j = 0; j < K; ++j) { sv[gidx*K + j] = tv[j]; si[gidx*K + j] = ti[j]; }
    }
    __syncthreads();
    if (tid == 0) {
        float bv[K]; int bi[K];
        #pragma unroll
        for (int j = 0; j < K; ++j) { bv[j] = -1e30f; bi[j] = 0; }
        for (int t = 0; t < GPB * K; ++t) {
            float c = sv[t]; int r = si[t];
            if (c > bv[K-1]) {
                bv[K-1] = c; bi[K-1] = r;
                #pragma unroll
                for (int j = K-1; j > 0; --j) {
                    if (bv[j] > bv[j-1]) {
                        float t2 = bv[j]; bv[j] = bv[j-1]; bv[j-1] = t2;
                        int   u2 = bi[j]; bi[j] = bi[j-1]; bi[j-1] = u2;
                    }
                }
            }
        }
        #pragma unroll
        for (int j = 0; j < K; ++j) {
            cand_v[blockIdx.x*K + j] = bv[j];
            cand_i[blockIdx.x*K + j] = bi[j];
        }
    }
}

// ---------------- Kernel B: reduce candidates to global top-10 ----------------
// Load all candidates into registers once; 10 in-register argmax passes.
__global__ __launch_bounds__(1024) void topk_final(
    const float* __restrict__ cand_v, const int* __restrict__ cand_i,
    int nc, float* __restrict__ out)
{
    __shared__ float rv[16];
    __shared__ int   rp[16];
    __shared__ float s_bv;
    __shared__ int   s_bp;

    const int tid  = threadIdx.x;
    const int lane = tid & 63;
    const int wid  = tid >> 6;

    float v[CPT];
    #pragma unroll
    for (int t = 0; t < CPT; ++t) {
        int idx = tid + t * 1024;
        v[t] = (idx < nc) ? cand_v[idx] : -3e38f;
    }

    for (int p = 0; p < K; ++p) {
        float bestv = -3e38f; int bestpos = 0x7fffffff;
        #pragma unroll
        for (int t = 0; t < CPT; ++t) {
            if (v[t] > bestv) { bestv = v[t]; bestpos = tid + t * 1024; }
        }
        #pragma unroll
        for (int m = 32; m >= 1; m >>= 1) {
            float ov = __shfl_xor(bestv, m, 64);
            int   op = __shfl_xor(bestpos, m, 64);
            if (ov > bestv || (ov == bestv && op < bestpos)) { bestv = ov; bestpos = op; }
        }
        if (lane == 0) { rv[wid] = bestv; rp[wid] = bestpos; }
        __syncthreads();
        if (tid == 0) {
            float bv = rv[0]; int bp = rp[0];
            for (int i = 1; i < 16; ++i)
                if (rv[i] > bv || (rv[i] == bv && rp[i] < bp)) { bv = rv[i]; bp = rp[i]; }
            s_bv = bv; s_bp = bp;
            out[p]     = bv;                      // value
            out[K + p] = (float)cand_i[bp];       // index (exact < 2^24)
        }
        __syncthreads();
        const int wbp = s_bp;
        #pragma unroll
        for (int t = 0; t < CPT; ++t) {
            if (tid + t * 1024 == wbp) v[t] = -3e38f;   // static index, predicated
        }
        __syncthreads();
    }
}

extern "C" void kernel_launch(void* const* d_in, const int* in_sizes, int n_in,
                              void* d_out, int out_size, void* d_ws, size_t ws_size,
                              hipStream_t stream) {
    const float* emb  = (const float*)d_in[0];
    const float* wvec = (const float*)d_in[1];
    const int V = in_sizes[0] / D;

    int nblocks = NBLOCKS;
    size_t need = (size_t)nblocks * K * 8;  // vals + idx
    if (need > ws_size) {
        nblocks = (int)(ws_size / (K * 8));
        if (nblocks < 1) nblocks = 1;
    }

    float* cand_v = (float*)d_ws;
    int*   cand_i = (int*)((float*)d_ws + (size_t)nblocks * K);

    cos_topk_partial<<<nblocks, 256, 0, stream>>>(emb, wvec, cand_v, cand_i,
                                                  V, nblocks * GPB);
    topk_final<<<1, 1024, 0, stream>>>(cand_v, cand_i, nblocks * K, (float*)d_out);
}

// Round 3
// 131.671 us; speedup vs baseline: 1.2200x; 1.0123x over previous
//
#include <hip/hip_runtime.h>

#define D    300
#define NF4  75            // 300 floats = 75 float4 per row
#define K    10
#define WPB  4             // waves per block
#define GPB  16            // 16-lane row-groups per block (4 per wave)
#define NBLOCKS 2048
#define CPT  20            // candidates per thread in final kernel (NBLOCKS*K/1024)

__device__ __forceinline__ float d4(float4 a, float4 b) {
    return a.x*b.x + a.y*b.y + a.z*b.z + a.w*b.w;
}

// ---------------- Kernel A: cosine + per-block top-10 candidates ----------------
// 16 lanes per row, 4 rows per wave per iteration, depth-2 register pipeline.
__global__ __launch_bounds__(256) void cos_topk_partial(
    const float* __restrict__ emb, const float* __restrict__ wvec,
    float* __restrict__ cand_v, int* __restrict__ cand_i,
    int V, int totalGroups)
{
    const int tid  = threadIdx.x;
    const int lane = tid & 63;
    const int wid  = tid >> 6;
    const int l16  = lane & 15;      // position within row-group
    const int rg   = lane >> 4;      // row-group 0..3 within wave
    const bool tl  = (l16 < NF4 - 64);   // tail-load lane mask (11 lanes)

    // Preload w
    const float4* w4p = (const float4*)wvec;
    float4 w0 = w4p[l16];
    float4 w1 = w4p[l16 + 16];
    float4 w2 = w4p[l16 + 32];
    float4 w3 = w4p[l16 + 48];
    float4 w4t = make_float4(0.f, 0.f, 0.f, 0.f);
    if (tl) w4t = w4p[l16 + 64];

    // q norm: 16-lane group reduce
    float qsq = d4(w0,w0) + d4(w1,w1) + d4(w2,w2) + d4(w3,w3) + d4(w4t,w4t);
    #pragma unroll
    for (int m = 8; m >= 1; m >>= 1) qsq += __shfl_xor(qsq, m, 64);
    const float qn = sqrtf(qsq);

    // per-group top-10
    float tv[K]; int ti[K];
    #pragma unroll
    for (int j = 0; j < K; ++j) { tv[j] = -1e30f; ti[j] = 0; }

    const int g0 = (blockIdx.x * WPB + wid) * 4 + rg;
    const int s  = totalGroups;

    // --- depth-2 pipelined main loop ---
    float4 A0, A1, A2, A3, A4, B0, B1, B2, B3, B4;
    A4 = make_float4(0.f,0.f,0.f,0.f);
    B4 = make_float4(0.f,0.f,0.f,0.f);

    if (g0 < V) {
        const float4* rp = (const float4*)(emb + (size_t)g0 * D);
        A0 = rp[l16]; A1 = rp[l16+16]; A2 = rp[l16+32]; A3 = rp[l16+48];
        if (tl) A4 = rp[l16+64];
    }
    if (g0 + s < V) {
        const float4* rp = (const float4*)(emb + (size_t)(g0 + s) * D);
        B0 = rp[l16]; B1 = rp[l16+16]; B2 = rp[l16+32]; B3 = rp[l16+48];
        if (tl) B4 = rp[l16+64];
    }

    #define BODY(C0,C1,C2,C3,C4,ROW)                                            \
    {                                                                            \
        float da = d4(C0, w0) + d4(C1, w1);                                      \
        float db = d4(C2, w2) + d4(C3, w3) + d4(C4, w4t);                        \
        float sa = d4(C0, C0) + d4(C1, C1);                                      \
        float sb = d4(C2, C2) + d4(C3, C3) + d4(C4, C4);                         \
        float dot = da + db;                                                     \
        float sq  = sa + sb;                                                     \
        _Pragma("unroll")                                                        \
        for (int m = 8; m >= 1; m >>= 1) {                                       \
            dot += __shfl_xor(dot, m, 64);                                       \
            sq  += __shfl_xor(sq,  m, 64);                                       \
        }                                                                        \
        float c = dot / (sqrtf(sq + 1e-9f) * qn);                                \
        if (c > tv[K-1]) {                                                       \
            tv[K-1] = c; ti[K-1] = (ROW);                                        \
            _Pragma("unroll")                                                    \
            for (int j = K-1; j > 0; --j) {                                      \
                if (tv[j] > tv[j-1]) {                                           \
                    float t = tv[j]; tv[j] = tv[j-1]; tv[j-1] = t;               \
                    int   u = ti[j]; ti[j] = ti[j-1]; ti[j-1] = u;               \
                }                                                                \
            }                                                                    \
        }                                                                        \
    }

    for (int r = g0; r < V; r += 2 * s) {
        // refill A for r+2s BEFORE consuming A's reduce/insert
        float4 N0=A0, N1=A1, N2=A2, N3=A3, N4=A4;
        if (r + 2*s < V) {
            const float4* rp = (const float4*)(emb + (size_t)(r + 2*s) * D);
            A0 = rp[l16]; A1 = rp[l16+16]; A2 = rp[l16+32]; A3 = rp[l16+48];
            if (tl) A4 = rp[l16+64];
        }
        BODY(N0, N1, N2, N3, N4, r)

        if (r + s < V) {
            float4 M0=B0, M1=B1, M2=B2, M3=B3, M4=B4;
            if (r + 3*s < V) {
                const float4* rp = (const float4*)(emb + (size_t)(r + 3*s) * D);
                B0 = rp[l16]; B1 = rp[l16+16]; B2 = rp[l16+32]; B3 = rp[l16+48];
                if (tl) B4 = rp[l16+64];
            }
            BODY(M0, M1, M2, M3, M4, r + s)
        }
    }
    #undef BODY

    // merge the block's 16 groups in LDS -> block top-10
    __shared__ float sv[GPB * K];
    __shared__ int   si[GPB * K];
    if (l16 == 0) {
        const int gidx = wid * 4 + rg;
        #pragma unroll
        for (int j = 0; j < K; ++j) { sv[gidx*K + j] = tv[j]; si[gidx*K + j] = ti[j]; }
    }
    __syncthreads();
    if (tid == 0) {
        float bv[K]; int bi[K];
        #pragma unroll
        for (int j = 0; j < K; ++j) { bv[j] = -1e30f; bi[j] = 0; }
        for (int t = 0; t < GPB * K; ++t) {
            float c = sv[t]; int r = si[t];
            if (c > bv[K-1]) {
                bv[K-1] = c; bi[K-1] = r;
                #pragma unroll
                for (int j = K-1; j > 0; --j) {
                    if (bv[j] > bv[j-1]) {
                        float t2 = bv[j]; bv[j] = bv[j-1]; bv[j-1] = t2;
                        int   u2 = bi[j]; bi[j] = bi[j-1]; bi[j-1] = u2;
                    }
                }
            }
        }
        #pragma unroll
        for (int j = 0; j < K; ++j) {
            cand_v[blockIdx.x*K + j] = bv[j];
            cand_i[blockIdx.x*K + j] = bi[j];
        }
    }
}

// ---------------- Kernel B: reduce candidates to global top-10 ----------------
__global__ __launch_bounds__(1024) void topk_final(
    const float* __restrict__ cand_v, const int* __restrict__ cand_i,
    int nc, float* __restrict__ out)
{
    __shared__ float rv[16];
    __shared__ int   rp[16];
    __shared__ float s_bv;
    __shared__ int   s_bp;

    const int tid  = threadIdx.x;
    const int lane = tid & 63;
    const int wid  = tid >> 6;

    float v[CPT];
    #pragma unroll
    for (int t = 0; t < CPT; ++t) {
        int idx = tid + t * 1024;
        v[t] = (idx < nc) ? cand_v[idx] : -3e38f;
    }

    for (int p = 0; p < K; ++p) {
        float bestv = -3e38f; int bestpos = 0x7fffffff;
        #pragma unroll
        for (int t = 0; t < CPT; ++t) {
            if (v[t] > bestv) { bestv = v[t]; bestpos = tid + t * 1024; }
        }
        #pragma unroll
        for (int m = 32; m >= 1; m >>= 1) {
            float ov = __shfl_xor(bestv, m, 64);
            int   op = __shfl_xor(bestpos, m, 64);
            if (ov > bestv || (ov == bestv && op < bestpos)) { bestv = ov; bestpos = op; }
        }
        if (lane == 0) { rv[wid] = bestv; rp[wid] = bestpos; }
        __syncthreads();
        if (tid == 0) {
            float bv = rv[0]; int bp = rp[0];
            for (int i = 1; i < 16; ++i)
                if (rv[i] > bv || (rv[i] == bv && rp[i] < bp)) { bv = rv[i]; bp = rp[i]; }
            s_bv = bv; s_bp = bp;
            out[p]     = bv;                      // value
            out[K + p] = (float)cand_i[bp];       // index (exact < 2^24)
        }
        __syncthreads();
        const int wbp = s_bp;
        #pragma unroll
        for (int t = 0; t < CPT; ++t) {
            if (tid + t * 1024 == wbp) v[t] = -3e38f;   // static index, predicated
        }
        __syncthreads();
    }
}

extern "C" void kernel_launch(void* const* d_in, const int* in_sizes, int n_in,
                              void* d_out, int out_size, void* d_ws, size_t ws_size,
                              hipStream_t stream) {
    const float* emb  = (const float*)d_in[0];
    const float* wvec = (const float*)d_in[1];
    const int V = in_sizes[0] / D;

    int nblocks = NBLOCKS;
    size_t need = (size_t)nblocks * K * 8;  // vals + idx
    if (need > ws_size) {
        nblocks = (int)(ws_size / (K * 8));
        if (nblocks < 1) nblocks = 1;
    }

    float* cand_v = (float*)d_ws;
    int*   cand_i = (int*)((float*)d_ws + (size_t)nblocks * K);

    cos_topk_partial<<<nblocks, 256, 0, stream>>>(emb, wvec, cand_v, cand_i,
                                                  V, nblocks * GPB);
    topk_final<<<1, 1024, 0, stream>>>(cand_v, cand_i, nblocks * K, (float*)d_out);
}